// Round 4
// baseline (449.547 us; speedup 1.0000x reference)
//
#include <hip/hip_runtime.h>

typedef __attribute__((ext_vector_type(8))) _Float16 half8;
typedef __attribute__((ext_vector_type(4))) _Float16 half4;
typedef __attribute__((ext_vector_type(4))) float floatx4;

#define DEVI __device__ __forceinline__

// ---------------- async global->LDS, 16B/lane ----------------
DEVI void gload_lds16(const _Float16* g, _Float16* l) {
    __builtin_amdgcn_global_load_lds(
        (const __attribute__((address_space(1))) void*)g,
        (__attribute__((address_space(3))) void*)l, 16, 0, 0);
}

#define WAITV(N) asm volatile("s_waitcnt vmcnt(" #N ")" ::: "memory")
#define BAR() __builtin_amdgcn_s_barrier()

// =====================================================================
// 256x256 GEMM, m201-style 8-phase schedule. R4: RELAXED FENCES.
// BK=64 K-tiles; LDS = 2 buffers x 4 units of 16KB (A-lo/A-hi/B-lo/B-hi).
// 8 waves (2M x 4N); per tile 4 phases of 16 MFMA:
//   { [q0: 8 B-frag reads] + 4 A-frag reads | stage 1 unit (2 loads) |
//     [q3: vmcnt(4)] | s_barrier | setprio(1) 16 MFMA setprio(0) | s_barrier }
// R4 change vs R3: NO sched_barrier / NO forced lgkmcnt(0). ds_reads are
// compiler-visible, so the compiler emits partial lgkm waits and overlaps
// the LDS drain with MFMA (m97-verified behavior); rule #18 applies only
// to inline-asm reads. Raw s_barrier still fences all cross-wave hazards:
//   A(T+1) staged q0/q1 -> dest last read T-1 q3, guarded by its barrier;
//   B(T+2) staged q2/q3 -> dest read this tile q0, guarded by q0-close.
// vmcnt ledger (per wave, 2 loads/phase): prologue 12 issued, WAITV(4);
// each tile issues 8, WAITV(4) at q3 retires A(T+1),B(T+1), keeps B(T+2).
// K compile-time -> staging addresses are shift/add only (R3 had runtime
// 64-bit muls per load). Chunk-XOR swizzle c = p ^ (r&7): 0 conflicts (R3).
// =====================================================================

template <int K>
DEVI void stage_unit(const _Float16* __restrict__ src, _Float16* dst, int tid) {
    const int s0 = tid, s1 = tid + 512;            // 1024 chunk-slots of 8 halfs
    const int r0 = s0 >> 3, c0 = (s0 & 7) ^ (r0 & 7);
    const int r1 = s1 >> 3, c1 = (s1 & 7) ^ (r1 & 7);
    gload_lds16(src + (size_t)r0 * K + c0 * 8, dst + s0 * 8);
    gload_lds16(src + (size_t)r1 * K + c1 * 8, dst + s1 * 8);
}

// stage unit u (0=A-lo,1=A-hi,2=B-lo,3=B-hi) of tile t (source clamped;
// target keeps original parity -> tail writes only freed units).
template <int K>
DEVI void stage_u(const _Float16* __restrict__ A, const _Float16* __restrict__ B,
                  _Float16* lds, int t, int u, int tid) {
    constexpr int NT = K >> 6;
    const int tt = t < NT ? t : NT - 1;
    const _Float16* sp = ((u < 2) ? A : B) + (size_t)((u & 1) * 128) * K + (size_t)tt * 64;
    stage_unit<K>(sp, lds + ((t & 1) * 4 + u) * 8192, tid);
}

template <int K>
DEVI void gemm8p(const _Float16* __restrict__ A, const _Float16* __restrict__ B,
                 _Float16* lds, floatx4 acc[8][4], int tid)
{
    const int lane = tid & 63, w = tid >> 6;
    const int wm = w >> 2, wn = w & 3;
    const int lr = lane & 15, quad = lane >> 4, xr = lr & 7;
    const int co0 = (quad ^ xr) << 3;          // kk=0: chunk quad
    const int co1 = ((4 + quad) ^ xr) << 3;    // kk=1: chunk 4+quad
    const int brow = (wn & 1) * 64;            // row base inside B unit
    const int aU = wm, bU = 2 + (wn >> 1);
    constexpr int NT = K >> 6;

    // prologue: T0 all 4 units, B units of T1
    stage_u<K>(A, B, lds, 0, 0, tid); stage_u<K>(A, B, lds, 0, 1, tid);
    stage_u<K>(A, B, lds, 0, 2, tid); stage_u<K>(A, B, lds, 0, 3, tid);
    stage_u<K>(A, B, lds, 1, 2, tid); stage_u<K>(A, B, lds, 1, 3, tid);
    WAITV(4);                                   // T0 landed; B(T1) in flight
    BAR();

    for (int T = 0; T < NT; ++T) {
        const _Float16* ua = lds + ((T & 1) * 4 + aU) * 8192;
        const _Float16* ub = lds + ((T & 1) * 4 + bU) * 8192;
        half8 bf[4][2];
#pragma unroll
        for (int q = 0; q < 4; ++q) {
            if (q == 0) {
#pragma unroll
                for (int ni = 0; ni < 4; ++ni) {
                    bf[ni][0] = *(const half8*)&ub[(brow + ni * 16 + lr) * 64 + co0];
                    bf[ni][1] = *(const half8*)&ub[(brow + ni * 16 + lr) * 64 + co1];
                }
            }
            half8 af[2][2];
#pragma unroll
            for (int m2 = 0; m2 < 2; ++m2) {
                af[m2][0] = *(const half8*)&ua[(q * 32 + m2 * 16 + lr) * 64 + co0];
                af[m2][1] = *(const half8*)&ua[(q * 32 + m2 * 16 + lr) * 64 + co1];
            }
            if      (q == 0) stage_u<K>(A, B, lds, T + 1, 0, tid);
            else if (q == 1) stage_u<K>(A, B, lds, T + 1, 1, tid);
            else if (q == 2) stage_u<K>(A, B, lds, T + 2, 2, tid);
            else           { stage_u<K>(A, B, lds, T + 2, 3, tid); WAITV(4); }
            BAR();
            __builtin_amdgcn_s_setprio(1);
#pragma unroll
            for (int kk = 0; kk < 2; ++kk)
#pragma unroll
                for (int m2 = 0; m2 < 2; ++m2)
#pragma unroll
                    for (int ni = 0; ni < 4; ++ni)
                        acc[2 * q + m2][ni] = __builtin_amdgcn_mfma_f32_16x16x32_f16(
                            af[m2][kk], bf[ni][kk], acc[2 * q + m2][ni], 0, 0, 0);
            __builtin_amdgcn_s_setprio(0);
            BAR();
        }
    }
    WAITV(0);   // drain tail stage loads before epilogue/endpgm
}

DEVI void zacc(floatx4 acc[8][4]) {
    const floatx4 zf = {0.f, 0.f, 0.f, 0.f};
#pragma unroll
    for (int mi = 0; mi < 8; ++mi)
#pragma unroll
        for (int ni = 0; ni < 4; ++ni) acc[mi][ni] = zf;
}

// ---------------- prep kernels (unchanged) ----------------
__global__ __launch_bounds__(256) void k_cast_x(const float* __restrict__ x, _Float16* __restrict__ xh) {
    size_t i = ((size_t)blockIdx.x * 256 + threadIdx.x) * 8;
    float4 v0 = *(const float4*)(x + i);
    float4 v1 = *(const float4*)(x + i + 4);
    float vv[8] = {v0.x, v0.y, v0.z, v0.w, v1.x, v1.y, v1.z, v1.w};
    half8 h;
#pragma unroll
    for (int j = 0; j < 8; ++j) h[j] = (_Float16)vv[j];
    *(half8*)(xh + i) = h;
}

__global__ __launch_bounds__(256) void k_prep_w(const float* __restrict__ w, _Float16* __restrict__ wh) {
    __shared__ float tile[32][33];
    const int n0 = blockIdx.x * 32, k0 = blockIdx.y * 32;
    const int t = threadIdx.x;
#pragma unroll
    for (int it = 0; it < 4; ++it) {
        int idx = it * 256 + t;
        int kk = idx >> 5, nn = idx & 31;
        tile[kk][nn] = w[(size_t)(k0 + kk) * 3072 + n0 + nn];
    }
    __syncthreads();
#pragma unroll
    for (int it = 0; it < 4; ++it) {
        int idx = it * 256 + t;
        int nn = idx >> 5, kk = idx & 31;
        wh[(size_t)(n0 + nn) * 1024 + k0 + kk] = (_Float16)tile[kk][nn];
    }
}

__global__ __launch_bounds__(256) void k_prep_ow(const float* __restrict__ ow, _Float16* __restrict__ owh) {
    size_t i = ((size_t)blockIdx.x * 256 + threadIdx.x) * 8;
    float4 v0 = *(const float4*)(ow + i);
    float4 v1 = *(const float4*)(ow + i + 4);
    float vv[8] = {v0.x, v0.y, v0.z, v0.w, v1.x, v1.y, v1.z, v1.w};
    half8 h;
#pragma unroll
    for (int j = 0; j < 8; ++j) h[j] = (_Float16)vv[j];
    *(half8*)(owh + i) = h;
}

// ---------------- qkv GEMM, 256x256 tile ----------------
__global__ __launch_bounds__(512, 2) void k_qkv256(
    const _Float16* __restrict__ xh, const _Float16* __restrict__ wh,
    _Float16* __restrict__ qh, _Float16* __restrict__ kh, _Float16* __restrict__ vT)
{
    __shared__ __align__(16) _Float16 L[65536];   // 128 KiB
    // bijective XCD swizzle (nwg = 768, %8 == 0)
    const int gx = gridDim.x;
    const int nwg = gx * gridDim.y;
    const int lin = blockIdx.x + gx * blockIdx.y;
    const int wg = (lin & 7) * (nwg >> 3) + (lin >> 3);
    const int m0 = (wg % gx) * 256, n0 = (wg / gx) * 256;
    const int tid = threadIdx.x;
    floatx4 acc[8][4];
    zacc(acc);
    gemm8p<1024>(xh + (size_t)m0 * 1024, wh + (size_t)n0 * 1024, L, acc, tid);

    const int lane = tid & 63, w = tid >> 6;
    const int lr = lane & 15, quad = lane >> 4;
    const int mb0 = m0 + (w >> 2) * 128 + quad * 4;
    const int nb0 = n0 + (w & 3) * 64 + lr;
    if (n0 < 1024) {            // q, scaled by 1/sqrt(1024)
#pragma unroll
        for (int mi = 0; mi < 8; ++mi)
#pragma unroll
            for (int ni = 0; ni < 4; ++ni)
#pragma unroll
                for (int r = 0; r < 4; ++r)
                    qh[(size_t)(mb0 + mi * 16 + r) * 1024 + (nb0 + ni * 16)] =
                        (_Float16)(acc[mi][ni][r] * 0.03125f);
    } else if (n0 < 2048) {     // k
#pragma unroll
        for (int mi = 0; mi < 8; ++mi)
#pragma unroll
            for (int ni = 0; ni < 4; ++ni)
#pragma unroll
                for (int r = 0; r < 4; ++r)
                    kh[(size_t)(mb0 + mi * 16 + r) * 1024 + (nb0 - 1024 + ni * 16)] =
                        (_Float16)acc[mi][ni][r];
    } else {                    // v, transposed: vT[b][e][seq]
#pragma unroll
        for (int mi = 0; mi < 8; ++mi)
#pragma unroll
            for (int ni = 0; ni < 4; ++ni) {
                int mb = mb0 + mi * 16;          // 4-aligned; tiles never cross batch
                int b = mb >> 11, ml = mb & 2047;
                int e = nb0 - 2048 + ni * 16;
                half4 pk;
#pragma unroll
                for (int r = 0; r < 4; ++r) pk[r] = (_Float16)acc[mi][ni][r];
                *(half4*)&vT[((size_t)b * 1024 + e) * 2048 + ml] = pk;
            }
    }
}

// ---------------- generic 256x256 fp16 GEMM (A,B row-major contiguous-K) ----
// EPI 0: fp16 out at C16[z*sCz + m*ldc + n]; EPI 1: fp32 out + bias
template <int EPI, int K>
__global__ __launch_bounds__(512, 2) void k_g256(
    const _Float16* __restrict__ Ab, const _Float16* __restrict__ Bb,
    _Float16* __restrict__ C16, float* __restrict__ C32, const float* __restrict__ bias,
    unsigned long long sAz, unsigned long long sBz, unsigned long long sCz, int ldc)
{
    __shared__ __align__(16) _Float16 L[65536];
    const int gx = gridDim.x, gy = gridDim.y;
    const int nwg = gx * gy * gridDim.z;        // all launches have nwg % 8 == 0
    const int lin = blockIdx.x + gx * (blockIdx.y + gy * blockIdx.z);
    const int wg = (lin & 7) * (nwg >> 3) + (lin >> 3);
    const int bx = wg % gx, by = (wg / gx) % gy, bz = wg / (gx * gy);
    const int m0 = bx * 256, n0 = by * 256;
    const int tid = threadIdx.x;
    floatx4 acc[8][4];
    zacc(acc);
    gemm8p<K>(Ab + (size_t)bz * sAz + (size_t)m0 * K,
              Bb + (size_t)bz * sBz + (size_t)n0 * K, L, acc, tid);

    const int lane = tid & 63, w = tid >> 6;
    const int lr = lane & 15, quad = lane >> 4;
    const int mb0 = m0 + (w >> 2) * 128 + quad * 4;
    const int nb0 = n0 + (w & 3) * 64 + lr;
#pragma unroll
    for (int mi = 0; mi < 8; ++mi)
#pragma unroll
        for (int ni = 0; ni < 4; ++ni)
#pragma unroll
            for (int r = 0; r < 4; ++r) {
                int m = mb0 + mi * 16 + r;
                int n = nb0 + ni * 16;
                if (EPI == 0)
                    C16[(size_t)bz * sCz + (size_t)m * ldc + n] = (_Float16)acc[mi][ni][r];
                else
                    C32[(size_t)m * ldc + n] = acc[mi][ni][r] + bias[n];
            }
}

// ---------------- softmax rows, fp16 in place (unchanged) ----------------
DEVI float wred_max(float v) {
#pragma unroll
    for (int o = 32; o; o >>= 1) v = fmaxf(v, __shfl_xor(v, o, 64));
    return v;
}
DEVI float wred_sum(float v) {
#pragma unroll
    for (int o = 32; o; o >>= 1) v += __shfl_xor(v, o, 64);
    return v;
}

__global__ __launch_bounds__(256) void k_softmax(_Float16* __restrict__ S) {
    const size_t row = blockIdx.x;
    _Float16* p = S + row * 2048;
    const int t = threadIdx.x;
    __shared__ float redm[4], reds[4];
    float v[8];
    float mx = -3.4e38f;
#pragma unroll
    for (int i = 0; i < 8; ++i) { v[i] = (float)p[t + i * 256]; mx = fmaxf(mx, v[i]); }
    mx = wred_max(mx);
    if ((t & 63) == 0) redm[t >> 6] = mx;
    __syncthreads();
    mx = fmaxf(fmaxf(redm[0], redm[1]), fmaxf(redm[2], redm[3]));
    float s = 0.f;
#pragma unroll
    for (int i = 0; i < 8; ++i) { v[i] = __expf(v[i] - mx); s += v[i]; }
    s = wred_sum(s);
    if ((t & 63) == 0) reds[t >> 6] = s;
    __syncthreads();
    s = reds[0] + reds[1] + reds[2] + reds[3];
    float inv = 1.0f / s;
#pragma unroll
    for (int i = 0; i < 8; ++i) p[t + i * 256] = (_Float16)(v[i] * inv);
}

// ---------------- launch ----------------
extern "C" void kernel_launch(void* const* d_in, const int* in_sizes, int n_in,
                              void* d_out, int out_size, void* d_ws, size_t ws_size,
                              hipStream_t stream) {
    const float* x  = (const float*)d_in[0];   // [8,2048,1024]
    const float* wq = (const float*)d_in[1];   // [1024,3072]
    const float* ow = (const float*)d_in[2];   // [1024,1024]
    const float* ob = (const float*)d_in[3];   // [1024]
    float* out = (float*)d_out;                // [8,2048,1024] fp32

    // workspace layout (bytes)
    char* ws = (char*)d_ws;
    _Float16* xh  = (_Float16*)(ws + 0);           // 32 MB (dead after qkv)
    _Float16* wh  = (_Float16*)(ws + 33554432);    // 6 MB  (dead after qkv)
    _Float16* S   = (_Float16*)(ws + 0);           // 64 MB [8][2048][2048] over xh+wh
    _Float16* qh  = (_Float16*)(ws + 67108864);    // 32 MB (scaled 1/32)
    _Float16* kh  = (_Float16*)(ws + 100663296);   // 32 MB
    _Float16* vT  = (_Float16*)(ws + 134217728);   // 32 MB [8][1024][2048]
    _Float16* owh = (_Float16*)(ws + 167772160);   // 2 MB
    _Float16* y   = qh;                            // qh dead after S-gemm

    if (ws_size < 180355072ull) return;  // clean fail instead of OOB corruption

    hipLaunchKernelGGL(k_cast_x, dim3(8192), dim3(256), 0, stream, x, xh);
    hipLaunchKernelGGL(k_prep_w, dim3(96, 32), dim3(256), 0, stream, wq, wh);
    hipLaunchKernelGGL(k_qkv256, dim3(64, 12), dim3(512), 0, stream, xh, wh, qh, kh, vT);
    // S = q k^T (over dead xh/wh region)
    hipLaunchKernelGGL((k_g256<0, 1024>), dim3(8, 8, 8), dim3(512), 0, stream,
                       qh, kh, S, (float*)nullptr, (const float*)nullptr,
                       2048ull * 1024, 2048ull * 1024, 2048ull * 2048, 2048);
    hipLaunchKernelGGL(k_prep_ow, dim3(512), dim3(256), 0, stream, ow, owh);
    hipLaunchKernelGGL(k_softmax, dim3(16384), dim3(256), 0, stream, S);
    // y = P V (y over dead qh region)
    hipLaunchKernelGGL((k_g256<0, 2048>), dim3(8, 4, 8), dim3(512), 0, stream,
                       S, vT, y, (float*)nullptr, (const float*)nullptr,
                       2048ull * 2048, 1024ull * 2048, 2048ull * 1024, 1024);
    // out = y ow^T + b
    hipLaunchKernelGGL((k_g256<1, 1024>), dim3(64, 4, 1), dim3(512), 0, stream,
                       y, owh, (_Float16*)nullptr, out, ob,
                       0ull, 0ull, 0ull, 1024);
}

// Round 5
// 431.703 us; speedup vs baseline: 1.0413x; 1.0413x over previous
//
#include <hip/hip_runtime.h>

typedef __attribute__((ext_vector_type(8))) _Float16 half8;
typedef __attribute__((ext_vector_type(4))) _Float16 half4;
typedef __attribute__((ext_vector_type(4))) float floatx4;

#define DEVI __device__ __forceinline__

// ---------------- async global->LDS, 16B/lane ----------------
DEVI void gload_lds16(const _Float16* g, _Float16* l) {
    __builtin_amdgcn_global_load_lds(
        (const __attribute__((address_space(1))) void*)g,
        (__attribute__((address_space(3))) void*)l, 16, 0, 0);
}

#define WAITV(N) asm volatile("s_waitcnt vmcnt(" #N ")" ::: "memory")
#define BAR() __builtin_amdgcn_s_barrier()

// =====================================================================
// 256x256 GEMM, 8-phase schedule (unchanged from R4). R5 change: XCD
// PATCH SWIZZLE only. R4 post-mortem: phase=1526cyc vs 621 MFMA floor;
// staging ran at 10.7 B/cyc/CU (= HBM/L3-class rate; 768MB@6.3TB/s)
// because the linear XCD chunk gave each XCD 64 distinct A-panels
// (32MB >> 4MB L2). Fix: each XCD gets a compact 2D grid patch
// (qkv/out: 8 M-tiles x all N, M-fastest; S/PV: XCD = batch) so the
// co-resident blocks' hot K-window (~384KB) lives in its L2 at
// ~56 B/cyc/CU. m201 reference proves >=19.9 B/cyc staging sustainable.
// =====================================================================

template <int K>
DEVI void stage_unit(const _Float16* __restrict__ src, _Float16* dst, int tid) {
    const int s0 = tid, s1 = tid + 512;            // 1024 chunk-slots of 8 halfs
    const int r0 = s0 >> 3, c0 = (s0 & 7) ^ (r0 & 7);
    const int r1 = s1 >> 3, c1 = (s1 & 7) ^ (r1 & 7);
    gload_lds16(src + (size_t)r0 * K + c0 * 8, dst + s0 * 8);
    gload_lds16(src + (size_t)r1 * K + c1 * 8, dst + s1 * 8);
}

// stage unit u (0=A-lo,1=A-hi,2=B-lo,3=B-hi) of tile t (source clamped;
// target keeps original parity -> tail writes only freed units).
template <int K>
DEVI void stage_u(const _Float16* __restrict__ A, const _Float16* __restrict__ B,
                  _Float16* lds, int t, int u, int tid) {
    constexpr int NT = K >> 6;
    const int tt = t < NT ? t : NT - 1;
    const _Float16* sp = ((u < 2) ? A : B) + (size_t)((u & 1) * 128) * K + (size_t)tt * 64;
    stage_unit<K>(sp, lds + ((t & 1) * 4 + u) * 8192, tid);
}

template <int K>
DEVI void gemm8p(const _Float16* __restrict__ A, const _Float16* __restrict__ B,
                 _Float16* lds, floatx4 acc[8][4], int tid)
{
    const int lane = tid & 63, w = tid >> 6;
    const int wm = w >> 2, wn = w & 3;
    const int lr = lane & 15, quad = lane >> 4, xr = lr & 7;
    const int co0 = (quad ^ xr) << 3;          // kk=0: chunk quad
    const int co1 = ((4 + quad) ^ xr) << 3;    // kk=1: chunk 4+quad
    const int brow = (wn & 1) * 64;            // row base inside B unit
    const int aU = wm, bU = 2 + (wn >> 1);
    constexpr int NT = K >> 6;

    // prologue: T0 all 4 units, B units of T1
    stage_u<K>(A, B, lds, 0, 0, tid); stage_u<K>(A, B, lds, 0, 1, tid);
    stage_u<K>(A, B, lds, 0, 2, tid); stage_u<K>(A, B, lds, 0, 3, tid);
    stage_u<K>(A, B, lds, 1, 2, tid); stage_u<K>(A, B, lds, 1, 3, tid);
    WAITV(4);                                   // T0 landed; B(T1) in flight
    BAR();

    for (int T = 0; T < NT; ++T) {
        const _Float16* ua = lds + ((T & 1) * 4 + aU) * 8192;
        const _Float16* ub = lds + ((T & 1) * 4 + bU) * 8192;
        half8 bf[4][2];
#pragma unroll
        for (int q = 0; q < 4; ++q) {
            if (q == 0) {
#pragma unroll
                for (int ni = 0; ni < 4; ++ni) {
                    bf[ni][0] = *(const half8*)&ub[(brow + ni * 16 + lr) * 64 + co0];
                    bf[ni][1] = *(const half8*)&ub[(brow + ni * 16 + lr) * 64 + co1];
                }
            }
            half8 af[2][2];
#pragma unroll
            for (int m2 = 0; m2 < 2; ++m2) {
                af[m2][0] = *(const half8*)&ua[(q * 32 + m2 * 16 + lr) * 64 + co0];
                af[m2][1] = *(const half8*)&ua[(q * 32 + m2 * 16 + lr) * 64 + co1];
            }
            if      (q == 0) stage_u<K>(A, B, lds, T + 1, 0, tid);
            else if (q == 1) stage_u<K>(A, B, lds, T + 1, 1, tid);
            else if (q == 2) stage_u<K>(A, B, lds, T + 2, 2, tid);
            else           { stage_u<K>(A, B, lds, T + 2, 3, tid); WAITV(4); }
            BAR();
            __builtin_amdgcn_s_setprio(1);
#pragma unroll
            for (int kk = 0; kk < 2; ++kk)
#pragma unroll
                for (int m2 = 0; m2 < 2; ++m2)
#pragma unroll
                    for (int ni = 0; ni < 4; ++ni)
                        acc[2 * q + m2][ni] = __builtin_amdgcn_mfma_f32_16x16x32_f16(
                            af[m2][kk], bf[ni][kk], acc[2 * q + m2][ni], 0, 0, 0);
            __builtin_amdgcn_s_setprio(0);
            BAR();
        }
    }
    WAITV(0);   // drain tail stage loads before epilogue/endpgm
}

DEVI void zacc(floatx4 acc[8][4]) {
    const floatx4 zf = {0.f, 0.f, 0.f, 0.f};
#pragma unroll
    for (int mi = 0; mi < 8; ++mi)
#pragma unroll
        for (int ni = 0; ni < 4; ++ni) acc[mi][ni] = zf;
}

// ---------------- prep kernels (unchanged) ----------------
__global__ __launch_bounds__(256) void k_cast_x(const float* __restrict__ x, _Float16* __restrict__ xh) {
    size_t i = ((size_t)blockIdx.x * 256 + threadIdx.x) * 8;
    float4 v0 = *(const float4*)(x + i);
    float4 v1 = *(const float4*)(x + i + 4);
    float vv[8] = {v0.x, v0.y, v0.z, v0.w, v1.x, v1.y, v1.z, v1.w};
    half8 h;
#pragma unroll
    for (int j = 0; j < 8; ++j) h[j] = (_Float16)vv[j];
    *(half8*)(xh + i) = h;
}

__global__ __launch_bounds__(256) void k_prep_w(const float* __restrict__ w, _Float16* __restrict__ wh) {
    __shared__ float tile[32][33];
    const int n0 = blockIdx.x * 32, k0 = blockIdx.y * 32;
    const int t = threadIdx.x;
#pragma unroll
    for (int it = 0; it < 4; ++it) {
        int idx = it * 256 + t;
        int kk = idx >> 5, nn = idx & 31;
        tile[kk][nn] = w[(size_t)(k0 + kk) * 3072 + n0 + nn];
    }
    __syncthreads();
#pragma unroll
    for (int it = 0; it < 4; ++it) {
        int idx = it * 256 + t;
        int nn = idx >> 5, kk = idx & 31;
        wh[(size_t)(n0 + nn) * 1024 + k0 + kk] = (_Float16)tile[kk][nn];
    }
}

__global__ __launch_bounds__(256) void k_prep_ow(const float* __restrict__ ow, _Float16* __restrict__ owh) {
    size_t i = ((size_t)blockIdx.x * 256 + threadIdx.x) * 8;
    float4 v0 = *(const float4*)(ow + i);
    float4 v1 = *(const float4*)(ow + i + 4);
    float vv[8] = {v0.x, v0.y, v0.z, v0.w, v1.x, v1.y, v1.z, v1.w};
    half8 h;
#pragma unroll
    for (int j = 0; j < 8; ++j) h[j] = (_Float16)vv[j];
    *(half8*)(owh + i) = h;
}

// ---------------- qkv GEMM, 256x256 tile ----------------
__global__ __launch_bounds__(512, 2) void k_qkv256(
    const _Float16* __restrict__ xh, const _Float16* __restrict__ wh,
    _Float16* __restrict__ qh, _Float16* __restrict__ kh, _Float16* __restrict__ vT)
{
    __shared__ __align__(16) _Float16 L[65536];   // 128 KiB
    // XCD patch swizzle: xcd = lin&7 owns M-tiles [8*xcd, 8*xcd+8) x all 12 N,
    // M-fastest -> 32 co-resident blocks form an 8M x 4N patch; hot K-window
    // = 12 panels x 64K x 256 x 2B ~ 384 KB << 4 MB per-XCD L2. Bijective:
    // grid 64x12 = 768, lin&7 in [0,8), j in [0,96).
    const int lin = blockIdx.x + 64 * blockIdx.y;
    const int xcd = lin & 7, j = lin >> 3;
    const int m0 = (xcd * 8 + (j & 7)) * 256, n0 = (j >> 3) * 256;
    const int tid = threadIdx.x;
    floatx4 acc[8][4];
    zacc(acc);
    gemm8p<1024>(xh + (size_t)m0 * 1024, wh + (size_t)n0 * 1024, L, acc, tid);

    const int lane = tid & 63, w = tid >> 6;
    const int lr = lane & 15, quad = lane >> 4;
    const int mb0 = m0 + (w >> 2) * 128 + quad * 4;
    const int nb0 = n0 + (w & 3) * 64 + lr;
    if (n0 < 1024) {            // q, scaled by 1/sqrt(1024)
#pragma unroll
        for (int mi = 0; mi < 8; ++mi)
#pragma unroll
            for (int ni = 0; ni < 4; ++ni)
#pragma unroll
                for (int r = 0; r < 4; ++r)
                    qh[(size_t)(mb0 + mi * 16 + r) * 1024 + (nb0 + ni * 16)] =
                        (_Float16)(acc[mi][ni][r] * 0.03125f);
    } else if (n0 < 2048) {     // k
#pragma unroll
        for (int mi = 0; mi < 8; ++mi)
#pragma unroll
            for (int ni = 0; ni < 4; ++ni)
#pragma unroll
                for (int r = 0; r < 4; ++r)
                    kh[(size_t)(mb0 + mi * 16 + r) * 1024 + (nb0 - 1024 + ni * 16)] =
                        (_Float16)acc[mi][ni][r];
    } else {                    // v, transposed: vT[b][e][seq]
#pragma unroll
        for (int mi = 0; mi < 8; ++mi)
#pragma unroll
            for (int ni = 0; ni < 4; ++ni) {
                int mb = mb0 + mi * 16;          // 4-aligned; tiles never cross batch
                int b = mb >> 11, ml = mb & 2047;
                int e = nb0 - 2048 + ni * 16;
                half4 pk;
#pragma unroll
                for (int r = 0; r < 4; ++r) pk[r] = (_Float16)acc[mi][ni][r];
                *(half4*)&vT[((size_t)b * 1024 + e) * 2048 + ml] = pk;
            }
    }
}

// ---------------- generic 256x256 fp16 GEMM (A,B row-major contiguous-K) ----
// EPI 0: fp16 out; EPI 1: fp32 out + bias.
// MODE 0 (gz==8): XCD = batch z; within batch M-fastest (j%gx, j/gx).
// MODE 1 (gz==1, gx%8==0): XCD owns M-tiles [8x,8x+8) x all N, M-fastest.
template <int EPI, int K, int MODE>
__global__ __launch_bounds__(512, 2) void k_g256(
    const _Float16* __restrict__ Ab, const _Float16* __restrict__ Bb,
    _Float16* __restrict__ C16, float* __restrict__ C32, const float* __restrict__ bias,
    unsigned long long sAz, unsigned long long sBz, unsigned long long sCz, int ldc)
{
    __shared__ __align__(16) _Float16 L[65536];
    const int gx = gridDim.x, gy = gridDim.y;
    const int lin = blockIdx.x + gx * (blockIdx.y + gy * blockIdx.z);
    const int xcd = lin & 7, j = lin >> 3;
    int bx, by, bz;
    if (MODE == 0) { bz = xcd; bx = j % gx; by = j / gx; }
    else           { bz = 0;   bx = xcd * (gx >> 3) + j % (gx >> 3); by = j / (gx >> 3); }
    const int m0 = bx * 256, n0 = by * 256;
    const int tid = threadIdx.x;
    floatx4 acc[8][4];
    zacc(acc);
    gemm8p<K>(Ab + (size_t)bz * sAz + (size_t)m0 * K,
              Bb + (size_t)bz * sBz + (size_t)n0 * K, L, acc, tid);

    const int lane = tid & 63, w = tid >> 6;
    const int lr = lane & 15, quad = lane >> 4;
    const int mb0 = m0 + (w >> 2) * 128 + quad * 4;
    const int nb0 = n0 + (w & 3) * 64 + lr;
#pragma unroll
    for (int mi = 0; mi < 8; ++mi)
#pragma unroll
        for (int ni = 0; ni < 4; ++ni)
#pragma unroll
            for (int r = 0; r < 4; ++r) {
                int m = mb0 + mi * 16 + r;
                int n = nb0 + ni * 16;
                if (EPI == 0)
                    C16[(size_t)bz * sCz + (size_t)m * ldc + n] = (_Float16)acc[mi][ni][r];
                else
                    C32[(size_t)m * ldc + n] = acc[mi][ni][r] + bias[n];
            }
}

// ---------------- softmax rows, fp16 in place (unchanged) ----------------
DEVI float wred_max(float v) {
#pragma unroll
    for (int o = 32; o; o >>= 1) v = fmaxf(v, __shfl_xor(v, o, 64));
    return v;
}
DEVI float wred_sum(float v) {
#pragma unroll
    for (int o = 32; o; o >>= 1) v += __shfl_xor(v, o, 64);
    return v;
}

__global__ __launch_bounds__(256) void k_softmax(_Float16* __restrict__ S) {
    const size_t row = blockIdx.x;
    _Float16* p = S + row * 2048;
    const int t = threadIdx.x;
    __shared__ float redm[4], reds[4];
    float v[8];
    float mx = -3.4e38f;
#pragma unroll
    for (int i = 0; i < 8; ++i) { v[i] = (float)p[t + i * 256]; mx = fmaxf(mx, v[i]); }
    mx = wred_max(mx);
    if ((t & 63) == 0) redm[t >> 6] = mx;
    __syncthreads();
    mx = fmaxf(fmaxf(redm[0], redm[1]), fmaxf(redm[2], redm[3]));
    float s = 0.f;
#pragma unroll
    for (int i = 0; i < 8; ++i) { v[i] = __expf(v[i] - mx); s += v[i]; }
    s = wred_sum(s);
    if ((t & 63) == 0) reds[t >> 6] = s;
    __syncthreads();
    s = reds[0] + reds[1] + reds[2] + reds[3];
    float inv = 1.0f / s;
#pragma unroll
    for (int i = 0; i < 8; ++i) p[t + i * 256] = (_Float16)(v[i] * inv);
}

// ---------------- launch ----------------
extern "C" void kernel_launch(void* const* d_in, const int* in_sizes, int n_in,
                              void* d_out, int out_size, void* d_ws, size_t ws_size,
                              hipStream_t stream) {
    const float* x  = (const float*)d_in[0];   // [8,2048,1024]
    const float* wq = (const float*)d_in[1];   // [1024,3072]
    const float* ow = (const float*)d_in[2];   // [1024,1024]
    const float* ob = (const float*)d_in[3];   // [1024]
    float* out = (float*)d_out;                // [8,2048,1024] fp32

    // workspace layout (bytes)
    char* ws = (char*)d_ws;
    _Float16* xh  = (_Float16*)(ws + 0);           // 32 MB (dead after qkv)
    _Float16* wh  = (_Float16*)(ws + 33554432);    // 6 MB  (dead after qkv)
    _Float16* S   = (_Float16*)(ws + 0);           // 64 MB [8][2048][2048] over xh+wh
    _Float16* qh  = (_Float16*)(ws + 67108864);    // 32 MB (scaled 1/32)
    _Float16* kh  = (_Float16*)(ws + 100663296);   // 32 MB
    _Float16* vT  = (_Float16*)(ws + 134217728);   // 32 MB [8][1024][2048]
    _Float16* owh = (_Float16*)(ws + 167772160);   // 2 MB
    _Float16* y   = qh;                            // qh dead after S-gemm

    if (ws_size < 180355072ull) return;  // clean fail instead of OOB corruption

    hipLaunchKernelGGL(k_cast_x, dim3(8192), dim3(256), 0, stream, x, xh);
    hipLaunchKernelGGL(k_prep_w, dim3(96, 32), dim3(256), 0, stream, wq, wh);
    hipLaunchKernelGGL(k_qkv256, dim3(64, 12), dim3(512), 0, stream, xh, wh, qh, kh, vT);
    // S = q k^T (over dead xh/wh region); XCD = batch
    hipLaunchKernelGGL((k_g256<0, 1024, 0>), dim3(8, 8, 8), dim3(512), 0, stream,
                       qh, kh, S, (float*)nullptr, (const float*)nullptr,
                       2048ull * 1024, 2048ull * 1024, 2048ull * 2048, 2048);
    hipLaunchKernelGGL(k_prep_ow, dim3(512), dim3(256), 0, stream, ow, owh);
    hipLaunchKernelGGL(k_softmax, dim3(16384), dim3(256), 0, stream, S);
    // y = P V (y over dead qh region); XCD = batch
    hipLaunchKernelGGL((k_g256<0, 2048, 0>), dim3(8, 4, 8), dim3(512), 0, stream,
                       S, vT, y, (float*)nullptr, (const float*)nullptr,
                       2048ull * 2048, 1024ull * 2048, 2048ull * 1024, 1024);
    // out = y ow^T + b; XCD = M-chunk
    hipLaunchKernelGGL((k_g256<1, 1024, 1>), dim3(64, 4, 1), dim3(512), 0, stream,
                       y, owh, (_Float16*)nullptr, out, ob,
                       0ull, 0ull, 0ull, 1024);
}

// Round 6
// 425.279 us; speedup vs baseline: 1.0571x; 1.0151x over previous
//
#include <hip/hip_runtime.h>

typedef __attribute__((ext_vector_type(8))) _Float16 half8;
typedef __attribute__((ext_vector_type(4))) _Float16 half4;
typedef __attribute__((ext_vector_type(4))) float floatx4;

#define DEVI __device__ __forceinline__

// ---------------- async global->LDS, 16B/lane ----------------
DEVI void gload_lds16(const _Float16* g, _Float16* l) {
    __builtin_amdgcn_global_load_lds(
        (const __attribute__((address_space(1))) void*)g,
        (__attribute__((address_space(3))) void*)l, 16, 0, 0);
}

#define WAITV(N) asm volatile("s_waitcnt vmcnt(" #N ")" ::: "memory")
#define BAR() __builtin_amdgcn_s_barrier()

// =====================================================================
// 256x256 GEMM. R6: ONE barrier pair per 64-K tile (was 4 in R3-R5).
// R5 post-mortem: per-phase barriers serialized the LDS-read pipe
// (96/32 ds_read_b128 x ~12cyc/CU) against the MFMA pipe (621cyc/SIMD)
// -> phase 1450cyc vs 621 floor, MfmaUtil 39%. Within a tile all 4
// phases read the SAME two stable LDS units, so the intra-tile barriers
// protect nothing. New tile loop:
//   { stage 4 units of T+1 (8 loads) | vmcnt(8) | bar |
//     24 ds_read_b128 + 64 MFMA, ONE compiler-scheduled region | bar }
// Compiler emits partial lgkm waits (m97-verified) -> read drain
// overlaps MFMA; wave stagger overlaps the pipes CU-wide.
// Hazards: every read feeds an MFMA before the closing bar (lgkm waits
// drain all reads pre-bar); stage(T+1) has opposite buffer parity and
// issues after T-1's closing bar => WAR safe. vmcnt(8) at tile top
// retires T's 8 loads (8 newest in flight = T+1's). Clamped tail stage
// keeps the ledger exact; WAITV(0) before epilogue.
// Chunk-XOR swizzle c = p ^ (r&7): 0 bank conflicts (R3-R5 measured).
// XCD patch swizzle kept from R5 (FETCH 202->74MB measured).
// =====================================================================

// stage unit u (0=A-lo,1=A-hi,2=B-lo,3=B-hi) of tile t (source clamped;
// dest parity (t&1) -> tail writes only freed, never-again-read space).
template <int K>
DEVI void stage_u(const _Float16* __restrict__ A, const _Float16* __restrict__ B,
                  _Float16* lds, int t, int u, int tid) {
    constexpr int NT = K >> 6;
    const int tt = t < NT ? t : NT - 1;
    const _Float16* sp = ((u < 2) ? A : B) + (size_t)((u & 1) * 128) * K + (size_t)tt * 64;
    _Float16* dst = lds + ((t & 1) * 4 + u) * 8192;
    const int s0 = tid, s1 = tid + 512;            // 1024 chunk-slots of 8 halfs
    const int r0 = s0 >> 3, c0 = (s0 & 7) ^ (r0 & 7);
    const int r1 = s1 >> 3, c1 = (s1 & 7) ^ (r1 & 7);
    gload_lds16(sp + (size_t)r0 * K + c0 * 8, dst + s0 * 8);
    gload_lds16(sp + (size_t)r1 * K + c1 * 8, dst + s1 * 8);
}

template <int K>
DEVI void gemmdp(const _Float16* __restrict__ A, const _Float16* __restrict__ B,
                 _Float16* lds, floatx4 acc[8][4], int tid)
{
    const int lane = tid & 63, w = tid >> 6;
    const int wm = w >> 2, wn = w & 3;
    const int lr = lane & 15, quad = lane >> 4, xr = lr & 7;
    const int co0 = (quad ^ xr) << 3;          // kk=0: chunk quad
    const int co1 = ((4 + quad) ^ xr) << 3;    // kk=1: chunk 4+quad
    const int brow = (wn & 1) * 64;            // row base inside B unit
    const int aU = wm, bU = 2 + (wn >> 1);
    constexpr int NT = K >> 6;

    // prologue: tile 0's 4 units in flight
    stage_u<K>(A, B, lds, 0, 0, tid); stage_u<K>(A, B, lds, 0, 1, tid);
    stage_u<K>(A, B, lds, 0, 2, tid); stage_u<K>(A, B, lds, 0, 3, tid);

    for (int T = 0; T < NT; ++T) {
        // stage next tile (clamped at tail) -- 8 loads, opposite parity
        stage_u<K>(A, B, lds, T + 1, 0, tid); stage_u<K>(A, B, lds, T + 1, 1, tid);
        stage_u<K>(A, B, lds, T + 1, 2, tid); stage_u<K>(A, B, lds, T + 1, 3, tid);
        WAITV(8);                               // T's 8 landed; T+1's in flight
        BAR();                                  // publish tile T

        const _Float16* ua = lds + ((T & 1) * 4 + aU) * 8192;
        const _Float16* ub = lds + ((T & 1) * 4 + bU) * 8192;
        half8 bf[4][2];
#pragma unroll
        for (int ni = 0; ni < 4; ++ni) {
            bf[ni][0] = *(const half8*)&ub[(brow + ni * 16 + lr) * 64 + co0];
            bf[ni][1] = *(const half8*)&ub[(brow + ni * 16 + lr) * 64 + co1];
        }
        half8 af[8][2];
#pragma unroll
        for (int mi = 0; mi < 8; ++mi) {
            af[mi][0] = *(const half8*)&ua[(mi * 16 + lr) * 64 + co0];
            af[mi][1] = *(const half8*)&ua[(mi * 16 + lr) * 64 + co1];
        }
        __builtin_amdgcn_s_setprio(1);
#pragma unroll
        for (int mi = 0; mi < 8; ++mi)          // mi-major: MFMA(mi) waits only
#pragma unroll
            for (int kk = 0; kk < 2; ++kk)      // on bf(8)+af[mi] -> later af
#pragma unroll
                for (int ni = 0; ni < 4; ++ni)  // reads drain under the MFMAs
                    acc[mi][ni] = __builtin_amdgcn_mfma_f32_16x16x32_f16(
                        af[mi][kk], bf[ni][kk], acc[mi][ni], 0, 0, 0);
        __builtin_amdgcn_s_setprio(0);
        BAR();                                  // all reads of parity T&1 done
    }
    WAITV(0);   // drain tail stage loads before epilogue/endpgm
}

DEVI void zacc(floatx4 acc[8][4]) {
    const floatx4 zf = {0.f, 0.f, 0.f, 0.f};
#pragma unroll
    for (int mi = 0; mi < 8; ++mi)
#pragma unroll
        for (int ni = 0; ni < 4; ++ni) acc[mi][ni] = zf;
}

// ---------------- prep kernels (unchanged) ----------------
__global__ __launch_bounds__(256) void k_cast_x(const float* __restrict__ x, _Float16* __restrict__ xh) {
    size_t i = ((size_t)blockIdx.x * 256 + threadIdx.x) * 8;
    float4 v0 = *(const float4*)(x + i);
    float4 v1 = *(const float4*)(x + i + 4);
    float vv[8] = {v0.x, v0.y, v0.z, v0.w, v1.x, v1.y, v1.z, v1.w};
    half8 h;
#pragma unroll
    for (int j = 0; j < 8; ++j) h[j] = (_Float16)vv[j];
    *(half8*)(xh + i) = h;
}

__global__ __launch_bounds__(256) void k_prep_w(const float* __restrict__ w, _Float16* __restrict__ wh) {
    __shared__ float tile[32][33];
    const int n0 = blockIdx.x * 32, k0 = blockIdx.y * 32;
    const int t = threadIdx.x;
#pragma unroll
    for (int it = 0; it < 4; ++it) {
        int idx = it * 256 + t;
        int kk = idx >> 5, nn = idx & 31;
        tile[kk][nn] = w[(size_t)(k0 + kk) * 3072 + n0 + nn];
    }
    __syncthreads();
#pragma unroll
    for (int it = 0; it < 4; ++it) {
        int idx = it * 256 + t;
        int nn = idx >> 5, kk = idx & 31;
        wh[(size_t)(n0 + nn) * 1024 + k0 + kk] = (_Float16)tile[kk][nn];
    }
}

__global__ __launch_bounds__(256) void k_prep_ow(const float* __restrict__ ow, _Float16* __restrict__ owh) {
    size_t i = ((size_t)blockIdx.x * 256 + threadIdx.x) * 8;
    float4 v0 = *(const float4*)(ow + i);
    float4 v1 = *(const float4*)(ow + i + 4);
    float vv[8] = {v0.x, v0.y, v0.z, v0.w, v1.x, v1.y, v1.z, v1.w};
    half8 h;
#pragma unroll
    for (int j = 0; j < 8; ++j) h[j] = (_Float16)vv[j];
    *(half8*)(owh + i) = h;
}

// ---------------- qkv GEMM, 256x256 tile ----------------
__global__ __launch_bounds__(512, 2) void k_qkv256(
    const _Float16* __restrict__ xh, const _Float16* __restrict__ wh,
    _Float16* __restrict__ qh, _Float16* __restrict__ kh, _Float16* __restrict__ vT)
{
    __shared__ __align__(16) _Float16 L[65536];   // 128 KiB
    // XCD patch swizzle: xcd = lin&7 owns M-tiles [8*xcd, 8*xcd+8) x all 12 N,
    // M-fastest; hot K-window ~384 KB << 4 MB per-XCD L2. Bijective (64x12).
    const int lin = blockIdx.x + 64 * blockIdx.y;
    const int xcd = lin & 7, j = lin >> 3;
    const int m0 = (xcd * 8 + (j & 7)) * 256, n0 = (j >> 3) * 256;
    const int tid = threadIdx.x;
    floatx4 acc[8][4];
    zacc(acc);
    gemmdp<1024>(xh + (size_t)m0 * 1024, wh + (size_t)n0 * 1024, L, acc, tid);

    const int lane = tid & 63, w = tid >> 6;
    const int lr = lane & 15, quad = lane >> 4;
    const int mb0 = m0 + (w >> 2) * 128 + quad * 4;
    const int nb0 = n0 + (w & 3) * 64 + lr;
    if (n0 < 1024) {            // q, scaled by 1/sqrt(1024)
#pragma unroll
        for (int mi = 0; mi < 8; ++mi)
#pragma unroll
            for (int ni = 0; ni < 4; ++ni)
#pragma unroll
                for (int r = 0; r < 4; ++r)
                    qh[(size_t)(mb0 + mi * 16 + r) * 1024 + (nb0 + ni * 16)] =
                        (_Float16)(acc[mi][ni][r] * 0.03125f);
    } else if (n0 < 2048) {     // k
#pragma unroll
        for (int mi = 0; mi < 8; ++mi)
#pragma unroll
            for (int ni = 0; ni < 4; ++ni)
#pragma unroll
                for (int r = 0; r < 4; ++r)
                    kh[(size_t)(mb0 + mi * 16 + r) * 1024 + (nb0 - 1024 + ni * 16)] =
                        (_Float16)acc[mi][ni][r];
    } else {                    // v, transposed: vT[b][e][seq]
#pragma unroll
        for (int mi = 0; mi < 8; ++mi)
#pragma unroll
            for (int ni = 0; ni < 4; ++ni) {
                int mb = mb0 + mi * 16;          // 4-aligned; tiles never cross batch
                int b = mb >> 11, ml = mb & 2047;
                int e = nb0 - 2048 + ni * 16;
                half4 pk;
#pragma unroll
                for (int r = 0; r < 4; ++r) pk[r] = (_Float16)acc[mi][ni][r];
                *(half4*)&vT[((size_t)b * 1024 + e) * 2048 + ml] = pk;
            }
    }
}

// ---------------- generic 256x256 fp16 GEMM (A,B row-major contiguous-K) ----
// EPI 0: fp16 out; EPI 1: fp32 out + bias.
// MODE 0 (gz==8): XCD = batch z; within batch M-fastest.
// MODE 1 (gz==1, gx%8==0): XCD owns M-tiles [8x,8x+8) x all N, M-fastest.
template <int EPI, int K, int MODE>
__global__ __launch_bounds__(512, 2) void k_g256(
    const _Float16* __restrict__ Ab, const _Float16* __restrict__ Bb,
    _Float16* __restrict__ C16, float* __restrict__ C32, const float* __restrict__ bias,
    unsigned long long sAz, unsigned long long sBz, unsigned long long sCz, int ldc)
{
    __shared__ __align__(16) _Float16 L[65536];
    const int gx = gridDim.x, gy = gridDim.y;
    const int lin = blockIdx.x + gx * (blockIdx.y + gy * blockIdx.z);
    const int xcd = lin & 7, j = lin >> 3;
    int bx, by, bz;
    if (MODE == 0) { bz = xcd; bx = j % gx; by = j / gx; }
    else           { bz = 0;   bx = xcd * (gx >> 3) + j % (gx >> 3); by = j / (gx >> 3); }
    const int m0 = bx * 256, n0 = by * 256;
    const int tid = threadIdx.x;
    floatx4 acc[8][4];
    zacc(acc);
    gemmdp<K>(Ab + (size_t)bz * sAz + (size_t)m0 * K,
              Bb + (size_t)bz * sBz + (size_t)n0 * K, L, acc, tid);

    const int lane = tid & 63, w = tid >> 6;
    const int lr = lane & 15, quad = lane >> 4;
    const int mb0 = m0 + (w >> 2) * 128 + quad * 4;
    const int nb0 = n0 + (w & 3) * 64 + lr;
#pragma unroll
    for (int mi = 0; mi < 8; ++mi)
#pragma unroll
        for (int ni = 0; ni < 4; ++ni)
#pragma unroll
            for (int r = 0; r < 4; ++r) {
                int m = mb0 + mi * 16 + r;
                int n = nb0 + ni * 16;
                if (EPI == 0)
                    C16[(size_t)bz * sCz + (size_t)m * ldc + n] = (_Float16)acc[mi][ni][r];
                else
                    C32[(size_t)m * ldc + n] = acc[mi][ni][r] + bias[n];
            }
}

// ---------------- softmax rows, fp16 in place (unchanged) ----------------
DEVI float wred_max(float v) {
#pragma unroll
    for (int o = 32; o; o >>= 1) v = fmaxf(v, __shfl_xor(v, o, 64));
    return v;
}
DEVI float wred_sum(float v) {
#pragma unroll
    for (int o = 32; o; o >>= 1) v += __shfl_xor(v, o, 64);
    return v;
}

__global__ __launch_bounds__(256) void k_softmax(_Float16* __restrict__ S) {
    const size_t row = blockIdx.x;
    _Float16* p = S + row * 2048;
    const int t = threadIdx.x;
    __shared__ float redm[4], reds[4];
    float v[8];
    float mx = -3.4e38f;
#pragma unroll
    for (int i = 0; i < 8; ++i) { v[i] = (float)p[t + i * 256]; mx = fmaxf(mx, v[i]); }
    mx = wred_max(mx);
    if ((t & 63) == 0) redm[t >> 6] = mx;
    __syncthreads();
    mx = fmaxf(fmaxf(redm[0], redm[1]), fmaxf(redm[2], redm[3]));
    float s = 0.f;
#pragma unroll
    for (int i = 0; i < 8; ++i) { v[i] = __expf(v[i] - mx); s += v[i]; }
    s = wred_sum(s);
    if ((t & 63) == 0) reds[t >> 6] = s;
    __syncthreads();
    s = reds[0] + reds[1] + reds[2] + reds[3];
    float inv = 1.0f / s;
#pragma unroll
    for (int i = 0; i < 8; ++i) p[t + i * 256] = (_Float16)(v[i] * inv);
}

// ---------------- launch ----------------
extern "C" void kernel_launch(void* const* d_in, const int* in_sizes, int n_in,
                              void* d_out, int out_size, void* d_ws, size_t ws_size,
                              hipStream_t stream) {
    const float* x  = (const float*)d_in[0];   // [8,2048,1024]
    const float* wq = (const float*)d_in[1];   // [1024,3072]
    const float* ow = (const float*)d_in[2];   // [1024,1024]
    const float* ob = (const float*)d_in[3];   // [1024]
    float* out = (float*)d_out;                // [8,2048,1024] fp32

    // workspace layout (bytes)
    char* ws = (char*)d_ws;
    _Float16* xh  = (_Float16*)(ws + 0);           // 32 MB (dead after qkv)
    _Float16* wh  = (_Float16*)(ws + 33554432);    // 6 MB  (dead after qkv)
    _Float16* S   = (_Float16*)(ws + 0);           // 64 MB [8][2048][2048] over xh+wh
    _Float16* qh  = (_Float16*)(ws + 67108864);    // 32 MB (scaled 1/32)
    _Float16* kh  = (_Float16*)(ws + 100663296);   // 32 MB
    _Float16* vT  = (_Float16*)(ws + 134217728);   // 32 MB [8][1024][2048]
    _Float16* owh = (_Float16*)(ws + 167772160);   // 2 MB
    _Float16* y   = qh;                            // qh dead after S-gemm

    if (ws_size < 180355072ull) return;  // clean fail instead of OOB corruption

    hipLaunchKernelGGL(k_cast_x, dim3(8192), dim3(256), 0, stream, x, xh);
    hipLaunchKernelGGL(k_prep_w, dim3(96, 32), dim3(256), 0, stream, wq, wh);
    hipLaunchKernelGGL(k_qkv256, dim3(64, 12), dim3(512), 0, stream, xh, wh, qh, kh, vT);
    // S = q k^T (over dead xh/wh region); XCD = batch
    hipLaunchKernelGGL((k_g256<0, 1024, 0>), dim3(8, 8, 8), dim3(512), 0, stream,
                       qh, kh, S, (float*)nullptr, (const float*)nullptr,
                       2048ull * 1024, 2048ull * 1024, 2048ull * 2048, 2048);
    hipLaunchKernelGGL(k_prep_ow, dim3(512), dim3(256), 0, stream, ow, owh);
    hipLaunchKernelGGL(k_softmax, dim3(16384), dim3(256), 0, stream, S);
    // y = P V (y over dead qh region); XCD = batch
    hipLaunchKernelGGL((k_g256<0, 2048, 0>), dim3(8, 4, 8), dim3(512), 0, stream,
                       S, vT, y, (float*)nullptr, (const float*)nullptr,
                       2048ull * 2048, 1024ull * 2048, 2048ull * 1024, 1024);
    // out = y ow^T + b; XCD = M-chunk
    hipLaunchKernelGGL((k_g256<1, 1024, 1>), dim3(64, 4, 1), dim3(512), 0, stream,
                       y, owh, (_Float16*)nullptr, out, ob,
                       0ull, 0ull, 0ull, 1024);
}